// Round 10
// baseline (211.433 us; speedup 1.0000x reference)
//
#include <hip/hip_runtime.h>
#include <math.h>

#define IMG_W 512
#define IMG_H 512
#define NPLANES 48      // 16 * 3
#define RROWS 64        // output rows per wave (512 = 64*8 exact)
#define NCHUNK 8        // 512 / RROWS
#define NSTRIP 8        // 512 / 64 cols
#define WPB 4           // waves per block (256 threads)
#define NGROUP (NCHUNK / WPB)                  // 2 chunk-groups per strip
#define NBLOCKS (NPLANES * NSTRIP * NGROUP)    // 768 blocks
#define NPAIRS (RROWS / 2 + 5)                 // 37 input row-pairs per wave
#define SSIM_C1 1e-4f
#define SSIM_C2 9e-4f

typedef float f32x2 __attribute__((ext_vector_type(2)));
typedef float f32x4 __attribute__((ext_vector_type(4)));

struct GW { float g[11]; };

__device__ __forceinline__ f32x2 splat2(float v) { return (f32x2){v, v}; }
__device__ __forceinline__ f32x2 fma2(f32x2 a, f32x2 b, f32x2 c) {
  return __builtin_elementwise_fma(a, b, c);
}

// Packed-layout Newton division (verified rounds 6/9).
__device__ __forceinline__ f32x2 fdiv_fast2(f32x2 n, f32x2 d) {
  f32x2 r = { __builtin_amdgcn_rcpf(d.x), __builtin_amdgcn_rcpf(d.y) };
  r = r * fma2(-d, r, splat2(2.0f));      // 1 Newton step on reciprocal
  f32x2 q = n * r;
  q = fma2(fma2(-d, q, n), r, q);         // residual correction
  return q;
}

// ORDERING NOTE (root cause of rounds 3/4 failures, fix verified round 5):
// the no-barrier LDS pipeline needs cross-lane write->read ordering; per
// thread the addresses are provably distinct, so the compiler may reorder
// ds ops. HW keeps a wave's DS ops in issue order -> a compiler-only fence
// per iteration (between stage-writes and conv-reads) suffices; with the
// double buffer it also pins the reverse direction at distance 2.
#define LDS_ORDER_FENCE() asm volatile("" ::: "memory")

// ROUND-10 CHANGE vs verified round 6 (93 us): precomputed product streams.
// The h-conv was re-forming per-pixel products (A^2, AF, ...) at every tap:
// 11 f32x2-ops x 11 taps = 121/iter. Each pixel's products were recomputed
// 11x (once per output column that reads it). Now the 7 minimal streams
//   A, B, F, S1=A^2+F^2, S2=B^2+F^2, AF, BF
// are computed ONCE per pixel at staging (~12 scalar ops) and stored in LDS;
// h-conv = 7 fma/tap = 77/iter. Ring/vertical/SSIM identical downstream
// (variance merge moved from ring-write to pixel level; conv linearity).
// LDS: 4 arrays in the round-6 layout family (f32x4 [2][80], measured
// conflict-free): (A0,A1,B0,B1) | (F0,F1,S1_0,S1_1) | (S2_0,S2_1,AF0,AF1)
// | f32x2 (BF0,BF1). 36 KB/block.
// Round-9 lesson: waves_per_eu(2,2) pin REGRESSED (104.6 us, occupancy
// 24.5->17.7%) and VGPR stayed 88 -> no AGPR-shuttle pathology; the 3rd
// co-resident block earns ~11%. Keep __launch_bounds__(256,2).
__global__ __launch_bounds__(256, 2) void ssim_main(
    const float* __restrict__ A, const float* __restrict__ B,
    const float* __restrict__ F, double* __restrict__ partials, GW gw)
{
  __shared__ f32x4 sAB[WPB][2][80];   // (A0,A1,B0,B1)
  __shared__ f32x4 sFS[WPB][2][80];   // (F0,F1,S1_0,S1_1)
  __shared__ f32x4 sSA[WPB][2][80];   // (S2_0,S2_1,AF0,AF1)
  __shared__ f32x2 sBF[WPB][2][80];   // (BF0,BF1)
  __shared__ double sred[WPB];
  const int b = blockIdx.x;
  const int plane = b / (NSTRIP * NGROUP);
  const int rem   = b % (NSTRIP * NGROUP);
  const int strip = rem / NGROUP;
  const int grp   = rem % NGROUP;
  const int wid = threadIdx.x >> 6;      // wave id 0..3
  const int t   = threadIdx.x & 63;      // lane id
  const int chunk = grp * WPB + wid;     // 0..7
  const int x0 = strip * 64;
  const int y0 = chunk * RROWS;
  const size_t pbase = (size_t)plane * (IMG_W * IMG_H);
  const float* Ap = A + pbase;
  const float* Bp = B + pbase;
  const float* Fp = F + pbase;

  // this wave's private LDS slices
  f32x4 (&mAB)[2][80] = sAB[wid];
  f32x4 (&mFS)[2][80] = sFS[wid];
  f32x4 (&mSA)[2][80] = sSA[wid];
  f32x2 (&mBF)[2][80] = sBF[wid];

  const int c  = x0 - 5 + t;                 // primary load column
  const bool cok = (c >= 0) && (c < IMG_W);
  const int c2 = c + 64;                     // halo column (lanes 0..9)
  const bool c2ok = (t < 10) && (c2 < IMG_W);

  // ring[stream][slot]: horizontally-convolved ROW PAIRS, slot = pair mod 6
  f32x2 ring[7][6];
  #pragma unroll
  for (int s = 0; s < 7; ++s)
    #pragma unroll
    for (int k = 0; k < 6; ++k) ring[s][k] = splat2(0.f);

  float acc = 0.f;

  // prefetch registers: 2 rows x 3 arrays x (primary + halo)
  float rA0,rB0,rF0,xA0,xB0,xF0, rA1,rB1,rF1,xA1,xB1,xF1;
  auto load_pair = [&](int ii) {
    const int yin0 = y0 - 5 + 2*ii;
    const int yin1 = yin0 + 1;
    const bool r0 = (yin0 >= 0) && (yin0 < IMG_H);
    const bool r1 = (yin1 >= 0) && (yin1 < IMG_H);
    const size_t o0 = (size_t)yin0 * IMG_W;
    const size_t o1 = (size_t)yin1 * IMG_W;
    rA0 = (r0 && cok) ? Ap[o0 + c] : 0.f;
    rB0 = (r0 && cok) ? Bp[o0 + c] : 0.f;
    rF0 = (r0 && cok) ? Fp[o0 + c] : 0.f;
    rA1 = (r1 && cok) ? Ap[o1 + c] : 0.f;
    rB1 = (r1 && cok) ? Bp[o1 + c] : 0.f;
    rF1 = (r1 && cok) ? Fp[o1 + c] : 0.f;
    xA0 = (r0 && c2ok) ? Ap[o0 + c2] : 0.f;
    xB0 = (r0 && c2ok) ? Bp[o0 + c2] : 0.f;
    xF0 = (r0 && c2ok) ? Fp[o0 + c2] : 0.f;
    xA1 = (r1 && c2ok) ? Ap[o1 + c2] : 0.f;
    xB1 = (r1 && c2ok) ? Bp[o1 + c2] : 0.f;
    xF1 = (r1 && c2ok) ? Fp[o1 + c2] : 0.f;
  };

  load_pair(0);   // preload pair 0

  for (int jj = 0; jj < 7; ++jj) {
    #pragma unroll
    for (int ph = 0; ph < 6; ++ph) {
      const int ii = jj * 6 + ph;            // pair counter; ii % 6 == ph
      if (ii < NPAIRS) {                     // 37 pairs = 74 input rows
        const int buf = ii & 1;
        // --- stage prefetched row pair + per-pixel product streams ---
        {
          const float f0sq = rF0*rF0, f1sq = rF1*rF1;
          mAB[buf][t] = (f32x4){rA0, rA1, rB0, rB1};
          mFS[buf][t] = (f32x4){rF0, rF1, fmaf(rA0,rA0,f0sq), fmaf(rA1,rA1,f1sq)};
          mSA[buf][t] = (f32x4){fmaf(rB0,rB0,f0sq), fmaf(rB1,rB1,f1sq),
                                rA0*rF0, rA1*rF1};
          mBF[buf][t] = (f32x2){rB0*rF0, rB1*rF1};
        }
        if (t < 10) {
          const float f0sq = xF0*xF0, f1sq = xF1*xF1;
          mAB[buf][t+64] = (f32x4){xA0, xA1, xB0, xB1};
          mFS[buf][t+64] = (f32x4){xF0, xF1, fmaf(xA0,xA0,f0sq), fmaf(xA1,xA1,f1sq)};
          mSA[buf][t+64] = (f32x4){fmaf(xB0,xB0,f0sq), fmaf(xB1,xB1,f1sq),
                                   xA0*xF0, xA1*xF1};
          mBF[buf][t+64] = (f32x2){xB0*xF0, xB1*xF1};
        }
        // pin LDS program order: writes above, reads below (see note)
        LDS_ORDER_FENCE();
        // --- issue NEXT pair's global loads; latency hidden under convs ---
        if (ii < NPAIRS - 1) load_pair(ii + 1);
        // --- horizontal 11-tap conv: 7 precomputed streams, 7 fma/tap ---
        f32x2 hA=splat2(0.f), hB=splat2(0.f), hF=splat2(0.f),
              hS1=splat2(0.f), hS2=splat2(0.f),
              hAF=splat2(0.f), hBF=splat2(0.f);
        #pragma unroll
        for (int k = 0; k < 11; ++k) {
          const f32x2 wv = splat2(gw.g[k]);
          const f32x4 ab = mAB[buf][t+k];     // ds_read_b128
          const f32x4 fs = mFS[buf][t+k];     // ds_read_b128
          const f32x4 sa = mSA[buf][t+k];     // ds_read_b128
          const f32x2 bf = mBF[buf][t+k];     // ds_read_b64
          hA  = fma2(wv, (f32x2){ab.x, ab.y}, hA);
          hB  = fma2(wv, (f32x2){ab.z, ab.w}, hB);
          hF  = fma2(wv, (f32x2){fs.x, fs.y}, hF);
          hS1 = fma2(wv, (f32x2){fs.z, fs.w}, hS1);
          hS2 = fma2(wv, (f32x2){sa.x, sa.y}, hS2);
          hAF = fma2(wv, (f32x2){sa.z, sa.w}, hAF);
          hBF = fma2(wv, bf, hBF);
        }
        // ring write (streams already merged at pixel level)
        ring[0][ph]=hA;  ring[1][ph]=hB;  ring[2][ph]=hF;
        ring[3][ph]=hS1; ring[4][ph]=hS2;
        ring[5][ph]=hAF; ring[6][ph]=hBF;

        // --- vertical 11-tap conv + packed SSIM map (unchanged) ---
        if (ii >= 5) {                       // output pair j = ii-5
          f32x2 M[7];
          #pragma unroll
          for (int s = 0; s < 7; ++s) M[s] = splat2(0.f);
          #pragma unroll
          for (int k = 0; k < 11; ++k) {
            const float w = gw.g[k];
            if ((k & 1) == 0) {
              // even tap: lo/hi rows use (.x,.y) of the SAME slot -> packed
              const int p = (ph + 1 + (k >> 1)) % 6;      // compile-time
              const f32x2 wv = splat2(w);
              #pragma unroll
              for (int s = 0; s < 7; ++s) M[s] = fma2(wv, ring[s][p], M[s]);
            } else {
              // odd tap: halves of adjacent slots; scalar on register halves
              const int plo = (ph + 1 + (k >> 1)) % 6;    // compile-time
              const int phi = (plo + 1) % 6;
              #pragma unroll
              for (int s = 0; s < 7; ++s) {
                M[s].x = fmaf(w, ring[s][plo].y, M[s].x);
                M[s].y = fmaf(w, ring[s][phi].x, M[s].y);
              }
            }
          }
          const f32x2 mAv=M[0], mBv=M[1], mFv=M[2];
          const f32x2 vS1=M[3], vS2=M[4], vAF=M[5], vBF=M[6];
          const f32x2 mA2=mAv*mAv, mB2=mBv*mBv, mF2=mFv*mFv,
                      mAF=mAv*mFv, mBF2=mBv*mFv;
          const f32x2 sAFv = vAF - mAF, sBFv = vBF - mBF2;
          const f32x2 ts1 = vS1 - mA2 - mF2;   // sigmaA^2 + sigmaF^2
          const f32x2 ts2 = vS2 - mB2 - mF2;   // sigmaB^2 + sigmaF^2
          const f32x2 two = splat2(2.f), c1 = splat2(SSIM_C1), c2v = splat2(SSIM_C2);
          const f32x2 n1 = fma2(two, mAF, c1) * fma2(two, sAFv, c2v);
          const f32x2 d1 = (mA2 + mF2 + c1) * (ts1 + c2v);
          const f32x2 n2 = fma2(two, mBF2, c1) * fma2(two, sBFv, c2v);
          const f32x2 d2 = (mB2 + mF2 + c1) * (ts2 + c2v);
          const f32x2 q1 = fdiv_fast2(n1, d1);
          const f32x2 q2 = fdiv_fast2(n2, d2);
          // accumulate in row-ascending order
          acc += q1.x + q2.x;
          acc += q1.y + q2.y;
        }
      }
    }
  }

  // wave (64-lane) reduction, then one cross-wave LDS reduce per block
  float wsum = acc;
  #pragma unroll
  for (int off = 32; off > 0; off >>= 1)
    wsum += __shfl_down(wsum, off, 64);
  if (t == 0) sred[wid] = (double)wsum;
  __syncthreads();
  if (threadIdx.x == 0)
    partials[b] = sred[0] + sred[1] + sred[2] + sred[3];
}

__global__ __launch_bounds__(256) void ssim_final(
    const double* __restrict__ partials, float* __restrict__ out)
{
  __shared__ double sd[256];
  const int t = threadIdx.x;
  double s = 0.0;
  for (int i = t; i < NBLOCKS; i += 256) s += partials[i];
  sd[t] = s;
  __syncthreads();
  for (int off = 128; off > 0; off >>= 1) {
    if (t < off) sd[t] += sd[t + off];
    __syncthreads();
  }
  if (t == 0)
    out[0] = (float)(0.5 * sd[0] / (double)(16.0 * 3.0 * 512.0 * 512.0));
}

extern "C" void kernel_launch(void* const* d_in, const int* in_sizes, int n_in,
                              void* d_out, int out_size, void* d_ws, size_t ws_size,
                              hipStream_t stream) {
  const float* A = (const float*)d_in[0];
  const float* B = (const float*)d_in[1];
  const float* F = (const float*)d_in[2];
  double* partials = (double*)d_ws;   // NBLOCKS doubles = 6 KB

  GW gw;
  double g[11], s = 0.0;
  for (int i = 0; i < 11; ++i) { g[i] = exp(-((double)((i-5)*(i-5))) / 4.5); s += g[i]; }
  for (int i = 0; i < 11; ++i) gw.g[i] = (float)(g[i] / s);

  hipLaunchKernelGGL(ssim_main, dim3(NBLOCKS), dim3(WPB * 64), 0, stream,
                     A, B, F, partials, gw);
  hipLaunchKernelGGL(ssim_final, dim3(1), dim3(256), 0, stream,
                     partials, (float*)d_out);
}

// Round 11
// 205.600 us; speedup vs baseline: 1.0284x; 1.0284x over previous
//
#include <hip/hip_runtime.h>
#include <math.h>

#define IMG_W 512
#define IMG_H 512
#define NPLANES 48      // 16 * 3
#define RROWS 64        // output rows per wave (512 = 64*8 exact)
#define NCHUNK 8        // 512 / RROWS
#define NSTRIP 8        // 512 / 64 cols
#define WPB 4           // waves per block (256 threads)
#define NGROUP (NCHUNK / WPB)                  // 2 chunk-groups per strip
#define NBLOCKS (NPLANES * NSTRIP * NGROUP)    // 768 blocks
#define NPAIRS (RROWS / 2 + 5)                 // 37 input row-pairs per wave
#define SSIM_C1 1e-4f
#define SSIM_C2 9e-4f

typedef float f32x2 __attribute__((ext_vector_type(2)));
typedef float f32x4 __attribute__((ext_vector_type(4)));

struct GW { float g[11]; };

__device__ __forceinline__ f32x2 splat2(float v) { return (f32x2){v, v}; }
__device__ __forceinline__ f32x2 fma2(f32x2 a, f32x2 b, f32x2 c) {
  return __builtin_elementwise_fma(a, b, c);   // scalarizes on this toolchain
}

// ---- ROUND-11 BISECT: plain VOP3P packed ops (NO neg modifiers), applied
// ONLY to the h-conv. Round 8 converted everything (incl. neg_lo/neg_hi
// forms in SSIM/division) and failed absmax 1.4e-3; round 9 exonerated the
// occupancy attribute. This round isolates: plain pk ops + largest prize
// chunk (h-conv = 242 of ~636 scalar instrs/iter). Pass -> plain VOP3P
// verified, neg-forms indicted. Fail -> all pk-asm condemned.
// Per-element IEEE semantics identical to the scalar sequence.
__device__ __forceinline__ f32x2 pk_mul(f32x2 a, f32x2 b) {
  f32x2 d;
  asm("v_pk_mul_f32 %0, %1, %2" : "=v"(d) : "v"(a), "v"(b));
  return d;
}
__device__ __forceinline__ f32x2 pk_add(f32x2 a, f32x2 b) {
  f32x2 d;
  asm("v_pk_add_f32 %0, %1, %2" : "=v"(d) : "v"(a), "v"(b));
  return d;
}
__device__ __forceinline__ f32x2 pk_fma(f32x2 a, f32x2 b, f32x2 c) {  // a*b+c
  f32x2 d;
  asm("v_pk_fma_f32 %0, %1, %2, %3" : "=v"(d) : "v"(a), "v"(b), "v"(c));
  return d;
}

// Packed-layout Newton division (verified rounds 6/9; scalarized codegen —
// deliberately NOT asm this round).
__device__ __forceinline__ f32x2 fdiv_fast2(f32x2 n, f32x2 d) {
  f32x2 r = { __builtin_amdgcn_rcpf(d.x), __builtin_amdgcn_rcpf(d.y) };
  r = r * fma2(-d, r, splat2(2.0f));      // 1 Newton step on reciprocal
  f32x2 q = n * r;
  q = fma2(fma2(-d, q, n), r, q);         // residual correction
  return q;
}

// ORDERING NOTE (root cause of rounds 3/4 failures, fix verified round 5):
// the no-barrier LDS pipeline needs cross-lane write->read ordering; per
// thread the addresses are provably distinct, so the compiler may reorder
// ds ops. HW keeps a wave's DS ops in issue order -> a compiler-only fence
// per iteration (between stage-writes and conv-reads) suffices; with the
// double buffer it also pins the reverse direction at distance 2.
#define LDS_ORDER_FENCE() asm volatile("" ::: "memory")

// Structure = verified round 6 (93 us). Round-10 lesson: do NOT trade VALU
// for LDS reads (ds_read_b128 ~12cyc; exchange rate ~4:1 against LDS here).
// Round-9 lesson: keep __launch_bounds__(256,2); waves_per_eu(2,2) pin
// regressed (lost the 3rd co-resident block).
__global__ __launch_bounds__(256, 2) void ssim_main(
    const float* __restrict__ A, const float* __restrict__ B,
    const float* __restrict__ F, double* __restrict__ partials, GW gw)
{
  __shared__ f32x4 sAB[WPB][2][80];   // (A0,A1,B0,B1) per column
  __shared__ f32x2 sFF[WPB][2][80];   // (F0,F1) per column
  __shared__ double sred[WPB];
  const int b = blockIdx.x;
  const int plane = b / (NSTRIP * NGROUP);
  const int rem   = b % (NSTRIP * NGROUP);
  const int strip = rem / NGROUP;
  const int grp   = rem % NGROUP;
  const int wid = threadIdx.x >> 6;      // wave id 0..3
  const int t   = threadIdx.x & 63;      // lane id
  const int chunk = grp * WPB + wid;     // 0..7
  const int x0 = strip * 64;
  const int y0 = chunk * RROWS;
  const size_t pbase = (size_t)plane * (IMG_W * IMG_H);
  const float* Ap = A + pbase;
  const float* Bp = B + pbase;
  const float* Fp = F + pbase;

  // this wave's private LDS slices
  f32x4 (&mAB)[2][80] = sAB[wid];
  f32x2 (&mFF)[2][80] = sFF[wid];

  const int c  = x0 - 5 + t;                 // primary load column
  const bool cok = (c >= 0) && (c < IMG_W);
  const int c2 = c + 64;                     // halo column (lanes 0..9)
  const bool c2ok = (t < 10) && (c2 < IMG_W);

  // ring[stream][slot]: horizontally-convolved ROW PAIRS, slot = pair mod 6
  f32x2 ring[7][6];
  #pragma unroll
  for (int s = 0; s < 7; ++s)
    #pragma unroll
    for (int k = 0; k < 6; ++k) ring[s][k] = splat2(0.f);

  float acc = 0.f;

  // prefetch registers: 2 rows x 3 arrays x (primary + halo)
  float rA0,rB0,rF0,xA0,xB0,xF0, rA1,rB1,rF1,xA1,xB1,xF1;
  auto load_pair = [&](int ii) {
    const int yin0 = y0 - 5 + 2*ii;
    const int yin1 = yin0 + 1;
    const bool r0 = (yin0 >= 0) && (yin0 < IMG_H);
    const bool r1 = (yin1 >= 0) && (yin1 < IMG_H);
    const size_t o0 = (size_t)yin0 * IMG_W;
    const size_t o1 = (size_t)yin1 * IMG_W;
    rA0 = (r0 && cok) ? Ap[o0 + c] : 0.f;
    rB0 = (r0 && cok) ? Bp[o0 + c] : 0.f;
    rF0 = (r0 && cok) ? Fp[o0 + c] : 0.f;
    rA1 = (r1 && cok) ? Ap[o1 + c] : 0.f;
    rB1 = (r1 && cok) ? Bp[o1 + c] : 0.f;
    rF1 = (r1 && cok) ? Fp[o1 + c] : 0.f;
    xA0 = (r0 && c2ok) ? Ap[o0 + c2] : 0.f;
    xB0 = (r0 && c2ok) ? Bp[o0 + c2] : 0.f;
    xF0 = (r0 && c2ok) ? Fp[o0 + c2] : 0.f;
    xA1 = (r1 && c2ok) ? Ap[o1 + c2] : 0.f;
    xB1 = (r1 && c2ok) ? Bp[o1 + c2] : 0.f;
    xF1 = (r1 && c2ok) ? Fp[o1 + c2] : 0.f;
  };

  load_pair(0);   // preload pair 0

  for (int jj = 0; jj < 7; ++jj) {
    #pragma unroll
    for (int ph = 0; ph < 6; ++ph) {
      const int ii = jj * 6 + ph;            // pair counter; ii % 6 == ph
      if (ii < NPAIRS) {                     // 37 pairs = 74 input rows
        const int buf = ii & 1;
        // --- stage prefetched row pair into LDS (vector, double-buffered) ---
        mAB[buf][t] = (f32x4){rA0, rA1, rB0, rB1};
        mFF[buf][t] = (f32x2){rF0, rF1};
        if (t < 10) {
          mAB[buf][t+64] = (f32x4){xA0, xA1, xB0, xB1};
          mFF[buf][t+64] = (f32x2){xF0, xF1};
        }
        // pin LDS program order: writes above, reads below (see note)
        LDS_ORDER_FENCE();
        // --- issue NEXT pair's global loads; latency hidden under convs ---
        if (ii < NPAIRS - 1) load_pair(ii + 1);
        // --- horizontal 11-tap conv: forced v_pk_* (plain ops only) ---
        f32x2 hA=splat2(0.f), hB=splat2(0.f), hF=splat2(0.f),
              hA2=splat2(0.f), hB2=splat2(0.f), hF2=splat2(0.f),
              hAF=splat2(0.f), hBF=splat2(0.f);
        #pragma unroll
        for (int k = 0; k < 11; ++k) {
          const float w = gw.g[k];
          const f32x4 ab = mAB[buf][t+k];     // 1x ds_read_b128
          const f32x2 f  = mFF[buf][t+k];     // 1x ds_read_b64
          const f32x2 a  = {ab.x, ab.y};
          const f32x2 bb = {ab.z, ab.w};
          const f32x2 wv = splat2(w);
          const f32x2 wa = pk_mul(wv, a), wb = pk_mul(wv, bb), wf = pk_mul(wv, f);
          hA = pk_add(hA, wa); hB = pk_add(hB, wb); hF = pk_add(hF, wf);
          hA2 = pk_fma(wa, a, hA2); hB2 = pk_fma(wb, bb, hB2); hF2 = pk_fma(wf, f, hF2);
          hAF = pk_fma(wa, f, hAF); hBF = pk_fma(wb, f, hBF);
        }
        // merge variance streams at ring-write (conv linearity): 7 rings
        ring[0][ph]=hA;  ring[1][ph]=hB;  ring[2][ph]=hF;
        ring[3][ph]=pk_add(hA2, hF2);  ring[4][ph]=pk_add(hB2, hF2);
        ring[5][ph]=hAF; ring[6][ph]=hBF;

        // --- vertical 11-tap conv + SSIM map (verified R6 code, untouched) ---
        if (ii >= 5) {                       // output pair j = ii-5
          f32x2 M[7];
          #pragma unroll
          for (int s = 0; s < 7; ++s) M[s] = splat2(0.f);
          #pragma unroll
          for (int k = 0; k < 11; ++k) {
            const float w = gw.g[k];
            if ((k & 1) == 0) {
              // even tap: lo/hi rows use (.x,.y) of the SAME slot -> packed
              const int p = (ph + 1 + (k >> 1)) % 6;      // compile-time
              const f32x2 wv = splat2(w);
              #pragma unroll
              for (int s = 0; s < 7; ++s) M[s] = fma2(wv, ring[s][p], M[s]);
            } else {
              // odd tap: halves of adjacent slots; scalar on register halves
              const int plo = (ph + 1 + (k >> 1)) % 6;    // compile-time
              const int phi = (plo + 1) % 6;
              #pragma unroll
              for (int s = 0; s < 7; ++s) {
                M[s].x = fmaf(w, ring[s][plo].y, M[s].x);
                M[s].y = fmaf(w, ring[s][phi].x, M[s].y);
              }
            }
          }
          const f32x2 mAv=M[0], mBv=M[1], mFv=M[2];
          const f32x2 vS1=M[3], vS2=M[4], vAF=M[5], vBF=M[6];
          const f32x2 mA2=mAv*mAv, mB2=mBv*mBv, mF2=mFv*mFv,
                      mAF=mAv*mFv, mBF=mBv*mFv;
          const f32x2 sAFv = vAF - mAF, sBFv = vBF - mBF;
          const f32x2 ts1 = vS1 - mA2 - mF2;   // sigmaA^2 + sigmaF^2
          const f32x2 ts2 = vS2 - mB2 - mF2;   // sigmaB^2 + sigmaF^2
          const f32x2 two = splat2(2.f), c1 = splat2(SSIM_C1), c2v = splat2(SSIM_C2);
          const f32x2 n1 = fma2(two, mAF, c1) * fma2(two, sAFv, c2v);
          const f32x2 d1 = (mA2 + mF2 + c1) * (ts1 + c2v);
          const f32x2 n2 = fma2(two, mBF, c1) * fma2(two, sBFv, c2v);
          const f32x2 d2 = (mB2 + mF2 + c1) * (ts2 + c2v);
          const f32x2 q1 = fdiv_fast2(n1, d1);
          const f32x2 q2 = fdiv_fast2(n2, d2);
          // accumulate in row-ascending order (bit-identical to scalar)
          acc += q1.x + q2.x;
          acc += q1.y + q2.y;
        }
      }
    }
  }

  // wave (64-lane) reduction, then one cross-wave LDS reduce per block
  float wsum = acc;
  #pragma unroll
  for (int off = 32; off > 0; off >>= 1)
    wsum += __shfl_down(wsum, off, 64);
  if (t == 0) sred[wid] = (double)wsum;
  __syncthreads();
  if (threadIdx.x == 0)
    partials[b] = sred[0] + sred[1] + sred[2] + sred[3];
}

__global__ __launch_bounds__(256) void ssim_final(
    const double* __restrict__ partials, float* __restrict__ out)
{
  __shared__ double sd[256];
  const int t = threadIdx.x;
  double s = 0.0;
  for (int i = t; i < NBLOCKS; i += 256) s += partials[i];
  sd[t] = s;
  __syncthreads();
  for (int off = 128; off > 0; off >>= 1) {
    if (t < off) sd[t] += sd[t + off];
    __syncthreads();
  }
  if (t == 0)
    out[0] = (float)(0.5 * sd[0] / (double)(16.0 * 3.0 * 512.0 * 512.0));
}

extern "C" void kernel_launch(void* const* d_in, const int* in_sizes, int n_in,
                              void* d_out, int out_size, void* d_ws, size_t ws_size,
                              hipStream_t stream) {
  const float* A = (const float*)d_in[0];
  const float* B = (const float*)d_in[1];
  const float* F = (const float*)d_in[2];
  double* partials = (double*)d_ws;   // NBLOCKS doubles = 6 KB

  GW gw;
  double g[11], s = 0.0;
  for (int i = 0; i < 11; ++i) { g[i] = exp(-((double)((i-5)*(i-5))) / 4.5); s += g[i]; }
  for (int i = 0; i < 11; ++i) gw.g[i] = (float)(g[i] / s);

  hipLaunchKernelGGL(ssim_main, dim3(NBLOCKS), dim3(WPB * 64), 0, stream,
                     A, B, F, partials, gw);
  hipLaunchKernelGGL(ssim_final, dim3(1), dim3(256), 0, stream,
                     partials, (float*)d_out);
}

// Round 12
// 191.453 us; speedup vs baseline: 1.1044x; 1.0739x over previous
//
#include <hip/hip_runtime.h>
#include <math.h>

#define IMG_W 512
#define IMG_H 512
#define NPLANES 48      // 16 * 3
#define RROWS 64        // output rows per wave (512 = 64*8 exact)
#define NCHUNK 8        // 512 / RROWS
#define NSTRIP 8        // 512 / 64 cols
#define WPB 4           // waves per block (256 threads)
#define NGROUP (NCHUNK / WPB)                  // 2 chunk-groups per strip
#define NBLOCKS (NPLANES * NSTRIP * NGROUP)    // 768 blocks
#define NPAIRS (RROWS / 2 + 5)                 // 37 input row-pairs per wave
#define SSIM_C1 1e-4f
#define SSIM_C2 9e-4f

typedef float f32x2 __attribute__((ext_vector_type(2)));
typedef float f32x4 __attribute__((ext_vector_type(4)));

struct GW { float g[11]; };

__device__ __forceinline__ f32x2 splat2(float v) { return (f32x2){v, v}; }
__device__ __forceinline__ f32x2 fma2(f32x2 a, f32x2 b, f32x2 c) {
  return __builtin_elementwise_fma(a, b, c);
}

// PACKING PROGRAM CLOSED (rounds 8/11): v_pk_*_f32 occupies the SIMD for 2x
// the cycles of the scalar op (157.3 TF spec = scalar rate: 256CU x 128lanes
// x 2FLOP x 2.4GHz). Packed f32 saves issue slots only; this kernel is not
// issue-bound (R11: forced pk-asm h-conv left VALU-busy TIME unchanged and
// regressed 93->108 us via lost SGPR-operand folding + register pressure).
// Keep the builtin form: VERIFIED and lets the compiler fold SGPR weights.

// Packed-layout Newton division (verified rounds 6/9).
__device__ __forceinline__ f32x2 fdiv_fast2(f32x2 n, f32x2 d) {
  f32x2 r = { __builtin_amdgcn_rcpf(d.x), __builtin_amdgcn_rcpf(d.y) };
  r = r * fma2(-d, r, splat2(2.0f));      // 1 Newton step on reciprocal
  f32x2 q = n * r;
  q = fma2(fma2(-d, q, n), r, q);         // residual correction
  return q;
}

// ORDERING NOTE (root cause of rounds 3/4 failures, fix verified round 5):
// the no-barrier LDS pipeline needs cross-lane write->read ordering; per
// thread the addresses are provably distinct, so the compiler may reorder
// ds ops. HW keeps a wave's DS ops in issue order -> a compiler-only fence
// per iteration (between stage-writes and conv-reads) suffices; with the
// double buffer it also pins the reverse direction at distance 2.
#define LDS_ORDER_FENCE() asm volatile("" ::: "memory")

// Structure = verified round 6 (93 us main). Banked lessons:
//  R7: latency decoupling (3-deep VMEM, 1-iter LDS distance) = null -> those
//      latencies were already hidden.
//  R9: waves_per_eu(2,2) pin regressed (lost 3rd co-resident block).
//  R10: trading VALU for ds_read_b128 regressed (~4:1 against LDS here).
//  R12 (this round): ssim_final dispatch folded into ssim_main via pre-scaled
//      float atomicAdd to out[0] (device-coherent; no fence/counter). 768
//      adds of ~3e-4 into ~0.8 -> ~2e-6 error, 100x under threshold.
__global__ __launch_bounds__(256, 2) void ssim_main(
    const float* __restrict__ A, const float* __restrict__ B,
    const float* __restrict__ F, float* __restrict__ out, GW gw)
{
  __shared__ f32x4 sAB[WPB][2][80];   // (A0,A1,B0,B1) per column
  __shared__ f32x2 sFF[WPB][2][80];   // (F0,F1) per column
  __shared__ double sred[WPB];
  const int b = blockIdx.x;
  const int plane = b / (NSTRIP * NGROUP);
  const int rem   = b % (NSTRIP * NGROUP);
  const int strip = rem / NGROUP;
  const int grp   = rem % NGROUP;
  const int wid = threadIdx.x >> 6;      // wave id 0..3
  const int t   = threadIdx.x & 63;      // lane id
  const int chunk = grp * WPB + wid;     // 0..7
  const int x0 = strip * 64;
  const int y0 = chunk * RROWS;
  const size_t pbase = (size_t)plane * (IMG_W * IMG_H);
  const float* Ap = A + pbase;
  const float* Bp = B + pbase;
  const float* Fp = F + pbase;

  // this wave's private LDS slices
  f32x4 (&mAB)[2][80] = sAB[wid];
  f32x2 (&mFF)[2][80] = sFF[wid];

  const int c  = x0 - 5 + t;                 // primary load column
  const bool cok = (c >= 0) && (c < IMG_W);
  const int c2 = c + 64;                     // halo column (lanes 0..9)
  const bool c2ok = (t < 10) && (c2 < IMG_W);

  // ring[stream][slot]: horizontally-convolved ROW PAIRS, slot = pair mod 6
  f32x2 ring[7][6];
  #pragma unroll
  for (int s = 0; s < 7; ++s)
    #pragma unroll
    for (int k = 0; k < 6; ++k) ring[s][k] = splat2(0.f);

  float acc = 0.f;

  // prefetch registers: 2 rows x 3 arrays x (primary + halo)
  float rA0,rB0,rF0,xA0,xB0,xF0, rA1,rB1,rF1,xA1,xB1,xF1;
  auto load_pair = [&](int ii) {
    const int yin0 = y0 - 5 + 2*ii;
    const int yin1 = yin0 + 1;
    const bool r0 = (yin0 >= 0) && (yin0 < IMG_H);
    const bool r1 = (yin1 >= 0) && (yin1 < IMG_H);
    const size_t o0 = (size_t)yin0 * IMG_W;
    const size_t o1 = (size_t)yin1 * IMG_W;
    rA0 = (r0 && cok) ? Ap[o0 + c] : 0.f;
    rB0 = (r0 && cok) ? Bp[o0 + c] : 0.f;
    rF0 = (r0 && cok) ? Fp[o0 + c] : 0.f;
    rA1 = (r1 && cok) ? Ap[o1 + c] : 0.f;
    rB1 = (r1 && cok) ? Bp[o1 + c] : 0.f;
    rF1 = (r1 && cok) ? Fp[o1 + c] : 0.f;
    xA0 = (r0 && c2ok) ? Ap[o0 + c2] : 0.f;
    xB0 = (r0 && c2ok) ? Bp[o0 + c2] : 0.f;
    xF0 = (r0 && c2ok) ? Fp[o0 + c2] : 0.f;
    xA1 = (r1 && c2ok) ? Ap[o1 + c2] : 0.f;
    xB1 = (r1 && c2ok) ? Bp[o1 + c2] : 0.f;
    xF1 = (r1 && c2ok) ? Fp[o1 + c2] : 0.f;
  };

  load_pair(0);   // preload pair 0

  for (int jj = 0; jj < 7; ++jj) {
    #pragma unroll
    for (int ph = 0; ph < 6; ++ph) {
      const int ii = jj * 6 + ph;            // pair counter; ii % 6 == ph
      if (ii < NPAIRS) {                     // 37 pairs = 74 input rows
        const int buf = ii & 1;
        // --- stage prefetched row pair into LDS (vector, double-buffered) ---
        mAB[buf][t] = (f32x4){rA0, rA1, rB0, rB1};
        mFF[buf][t] = (f32x2){rF0, rF1};
        if (t < 10) {
          mAB[buf][t+64] = (f32x4){xA0, xA1, xB0, xB1};
          mFF[buf][t+64] = (f32x2){xF0, xF1};
        }
        // pin LDS program order: writes above, reads below (see note)
        LDS_ORDER_FENCE();
        // --- issue NEXT pair's global loads; latency hidden under convs ---
        if (ii < NPAIRS - 1) load_pair(ii + 1);
        // --- horizontal 11-tap conv, packed layout over the 2 rows ---
        f32x2 hA=splat2(0.f), hB=splat2(0.f), hF=splat2(0.f),
              hA2=splat2(0.f), hB2=splat2(0.f), hF2=splat2(0.f),
              hAF=splat2(0.f), hBF=splat2(0.f);
        #pragma unroll
        for (int k = 0; k < 11; ++k) {
          const float w = gw.g[k];
          const f32x4 ab = mAB[buf][t+k];     // 1x ds_read_b128
          const f32x2 f  = mFF[buf][t+k];     // 1x ds_read_b64
          const f32x2 a  = {ab.x, ab.y};
          const f32x2 bb = {ab.z, ab.w};
          const f32x2 wv = splat2(w);
          const f32x2 wa = wv*a, wb = wv*bb, wf = wv*f;
          hA += wa; hB += wb; hF += wf;
          hA2 = fma2(wa, a, hA2); hB2 = fma2(wb, bb, hB2); hF2 = fma2(wf, f, hF2);
          hAF = fma2(wa, f, hAF); hBF = fma2(wb, f, hBF);
        }
        // merge variance streams at ring-write (conv linearity): 7 rings
        ring[0][ph]=hA;  ring[1][ph]=hB;  ring[2][ph]=hF;
        ring[3][ph]=hA2+hF2;  ring[4][ph]=hB2+hF2;
        ring[5][ph]=hAF; ring[6][ph]=hBF;

        // --- vertical 11-tap conv + packed SSIM map ---
        if (ii >= 5) {                       // output pair j = ii-5
          f32x2 M[7];
          #pragma unroll
          for (int s = 0; s < 7; ++s) M[s] = splat2(0.f);
          #pragma unroll
          for (int k = 0; k < 11; ++k) {
            const float w = gw.g[k];
            if ((k & 1) == 0) {
              // even tap: lo/hi rows use (.x,.y) of the SAME slot -> packed
              const int p = (ph + 1 + (k >> 1)) % 6;      // compile-time
              const f32x2 wv = splat2(w);
              #pragma unroll
              for (int s = 0; s < 7; ++s) M[s] = fma2(wv, ring[s][p], M[s]);
            } else {
              // odd tap: halves of adjacent slots; scalar on register halves
              const int plo = (ph + 1 + (k >> 1)) % 6;    // compile-time
              const int phi = (plo + 1) % 6;
              #pragma unroll
              for (int s = 0; s < 7; ++s) {
                M[s].x = fmaf(w, ring[s][plo].y, M[s].x);
                M[s].y = fmaf(w, ring[s][phi].x, M[s].y);
              }
            }
          }
          const f32x2 mAv=M[0], mBv=M[1], mFv=M[2];
          const f32x2 vS1=M[3], vS2=M[4], vAF=M[5], vBF=M[6];
          const f32x2 mA2=mAv*mAv, mB2=mBv*mBv, mF2=mFv*mFv,
                      mAF=mAv*mFv, mBF=mBv*mFv;
          const f32x2 sAFv = vAF - mAF, sBFv = vBF - mBF;
          const f32x2 ts1 = vS1 - mA2 - mF2;   // sigmaA^2 + sigmaF^2
          const f32x2 ts2 = vS2 - mB2 - mF2;   // sigmaB^2 + sigmaF^2
          const f32x2 two = splat2(2.f), c1 = splat2(SSIM_C1), c2v = splat2(SSIM_C2);
          const f32x2 n1 = fma2(two, mAF, c1) * fma2(two, sAFv, c2v);
          const f32x2 d1 = (mA2 + mF2 + c1) * (ts1 + c2v);
          const f32x2 n2 = fma2(two, mBF, c1) * fma2(two, sBFv, c2v);
          const f32x2 d2 = (mB2 + mF2 + c1) * (ts2 + c2v);
          const f32x2 q1 = fdiv_fast2(n1, d1);
          const f32x2 q2 = fdiv_fast2(n2, d2);
          // accumulate in row-ascending order (bit-identical to scalar)
          acc += q1.x + q2.x;
          acc += q1.y + q2.y;
        }
      }
    }
  }

  // wave (64-lane) reduction, cross-wave LDS reduce, then ONE pre-scaled
  // float atomicAdd per block straight into out[0] (R12: ssim_final fused
  // away; atomicAdd is device-coherent across XCDs, no fence needed; the
  // harness memsets out to 0 before the verification launch).
  float wsum = acc;
  #pragma unroll
  for (int off = 32; off > 0; off >>= 1)
    wsum += __shfl_down(wsum, off, 64);
  if (t == 0) sred[wid] = (double)wsum;
  __syncthreads();
  if (threadIdx.x == 0) {
    const double bsum = sred[0] + sred[1] + sred[2] + sred[3];
    atomicAdd(out, (float)(0.5 * bsum / (double)(16.0 * 3.0 * 512.0 * 512.0)));
  }
}

extern "C" void kernel_launch(void* const* d_in, const int* in_sizes, int n_in,
                              void* d_out, int out_size, void* d_ws, size_t ws_size,
                              hipStream_t stream) {
  const float* A = (const float*)d_in[0];
  const float* B = (const float*)d_in[1];
  const float* F = (const float*)d_in[2];

  GW gw;
  double g[11], s = 0.0;
  for (int i = 0; i < 11; ++i) { g[i] = exp(-((double)((i-5)*(i-5))) / 4.5); s += g[i]; }
  for (int i = 0; i < 11; ++i) gw.g[i] = (float)(g[i] / s);

  hipLaunchKernelGGL(ssim_main, dim3(NBLOCKS), dim3(WPB * 64), 0, stream,
                     A, B, F, (float*)d_out, gw);
}